// Round 1
// baseline (532.797 us; speedup 1.0000x reference)
//
#include <hip/hip_runtime.h>

// VQ argmin: exact bit-level emulation of numpy fp32 reference:
//   A = np.sum(flat*flat, axis=1)        (numpy pairwise-sum tree, fp32)
//   M2 = (2*flat) @ emb.T                (BLAS: sequential fp32 fma chain over d)
//   d = (A - M2) + ee;  argmin_k (first-min ties)
// z_e_x: [B=16, D=256, H=64, W=64] fp32; embedding: [K=1024, D=256] fp32
// out: int32 [65536]

#define D_DIM 256
#define K_DIM 1024
#define HW    4096          // H*W
#define N_TOT 65536
#define BN    128           // n-tile per block
#define BK    128           // k-tile per pass
#define DC    32            // d chunk staged in LDS
#define LDP   132           // padded LDS row stride (floats), keeps 16B alignment

// ---- numpy pairwise_sum replication (n=256 = two 128-blocks of 8 accumulators)

__global__ void ee_kernel(const float* __restrict__ e, float* __restrict__ ee) {
#pragma clang fp contract(off)
    int k = blockIdx.x * blockDim.x + threadIdx.x;
    if (k >= K_DIM) return;
    const float* row = e + (size_t)k * D_DIM;
    float total = 0.0f;
    #pragma unroll
    for (int h = 0; h < 2; ++h) {
        const float* a = row + h * 128;
        float r[8];
        #pragma unroll
        for (int j = 0; j < 8; ++j) { float v = a[j]; r[j] = v * v; }
        #pragma unroll
        for (int i = 8; i < 128; i += 8) {
            #pragma unroll
            for (int j = 0; j < 8; ++j) { float v = a[i + j]; r[j] = r[j] + v * v; }
        }
        float s = ((r[0] + r[1]) + (r[2] + r[3])) + ((r[4] + r[5]) + (r[6] + r[7]));
        total = (h == 0) ? s : (total + s);
    }
    ee[k] = total;
}

__global__ void a_kernel(const float* __restrict__ z, float* __restrict__ A) {
#pragma clang fp contract(off)
    int n = blockIdx.x * blockDim.x + threadIdx.x;   // grid covers exactly N_TOT
    int b  = n >> 12;
    int hw = n & (HW - 1);
    const float* base = z + (size_t)b * D_DIM * HW + hw;
    float total = 0.0f;
    #pragma unroll
    for (int h = 0; h < 2; ++h) {
        float r[8];
        #pragma unroll
        for (int j = 0; j < 8; ++j) {
            float v = base[(size_t)(h * 128 + j) * HW];
            r[j] = v * v;
        }
        #pragma unroll
        for (int i = 8; i < 128; i += 8) {
            #pragma unroll
            for (int j = 0; j < 8; ++j) {
                float v = base[(size_t)(h * 128 + i + j) * HW];
                r[j] = r[j] + v * v;
            }
        }
        float s = ((r[0] + r[1]) + (r[2] + r[3])) + ((r[4] + r[5]) + (r[6] + r[7]));
        total = (h == 0) ? s : (total + s);
    }
    A[n] = total;
}

// ---- main kernel: 128n x 128k register-blocked, 8x8 acc/thread, argmin epilogue

__launch_bounds__(256)
__global__ void vq_kernel(const float* __restrict__ z, const float* __restrict__ emb,
                          const float* __restrict__ A, const float* __restrict__ ee,
                          int* __restrict__ out) {
#pragma clang fp contract(off)
    __shared__ __align__(16) float zs[DC * LDP];   // holds 2*z, [dd][n]
    __shared__ __align__(16) float es[DC * LDP];   // [dd][k]

    const int tid = threadIdx.x;
    const int tx = tid & 15;        // k-group
    const int ty = tid >> 4;        // n-group
    const int n0 = blockIdx.x * BN;
    const int b   = n0 >> 12;       // BN=128 divides HW=4096: tile never crosses b
    const int hw0 = n0 & (HW - 1);
    const float* zbase = z + (size_t)b * D_DIM * HW + hw0;

    float bestv[8];
    int   bestk[8];
    #pragma unroll
    for (int i = 0; i < 8; ++i) { bestv[i] = 3.402823466e38f; bestk[i] = 0; }

    for (int kt = 0; kt < K_DIM / BK; ++kt) {
        float acc[8][8];
        #pragma unroll
        for (int i = 0; i < 8; ++i)
            #pragma unroll
            for (int j = 0; j < 8; ++j) acc[i][j] = 0.0f;

        for (int c = 0; c < D_DIM / DC; ++c) {
            const int d0 = c * DC;
            __syncthreads();   // previous chunk's reads complete
            // stage z tile (scaled by 2): 32 d x 128 n, coalesced float4
            #pragma unroll
            for (int q = 0; q < 4; ++q) {
                int fidx = tid + 256 * q;
                int dl = fidx >> 5, n4 = (fidx & 31) * 4;
                float4 v = *(const float4*)(zbase + (size_t)(d0 + dl) * HW + n4);
                float4 w;
                w.x = 2.0f * v.x; w.y = 2.0f * v.y; w.z = 2.0f * v.z; w.w = 2.0f * v.w;
                *(float4*)&zs[dl * LDP + n4] = w;
            }
            // stage e tile transposed: 32 d x 128 k
            #pragma unroll
            for (int r = 0; r < 4; ++r) {
                int kl = (tid >> 3) + 32 * r;
                int dq = tid & 7;
                float4 v = *(const float4*)(emb + (size_t)(kt * BK + kl) * D_DIM + d0 + dq * 4);
                es[(dq * 4 + 0) * LDP + kl] = v.x;
                es[(dq * 4 + 1) * LDP + kl] = v.y;
                es[(dq * 4 + 2) * LDP + kl] = v.z;
                es[(dq * 4 + 3) * LDP + kl] = v.w;
            }
            __syncthreads();
            // inner product: single sequential fma chain per (n,k), d ascending
            #pragma unroll 4
            for (int dd = 0; dd < DC; ++dd) {
                float4 z0 = *(const float4*)&zs[dd * LDP + 4 * ty];
                float4 z1 = *(const float4*)&zs[dd * LDP + 64 + 4 * ty];
                float4 e0 = *(const float4*)&es[dd * LDP + 4 * tx];
                float4 e1 = *(const float4*)&es[dd * LDP + 64 + 4 * tx];
                float zr[8] = {z0.x, z0.y, z0.z, z0.w, z1.x, z1.y, z1.z, z1.w};
                float er[8] = {e0.x, e0.y, e0.z, e0.w, e1.x, e1.y, e1.z, e1.w};
                #pragma unroll
                for (int i = 0; i < 8; ++i)
                    #pragma unroll
                    for (int j = 0; j < 8; ++j)
                        acc[i][j] = fmaf(zr[i], er[j], acc[i][j]);
            }
        }
        // epilogue for this k-tile: dist = (A - M2) + ee, fp32 chain like numpy
        #pragma unroll
        for (int i = 0; i < 8; ++i) {
            int nl = (i < 4) ? (4 * ty + i) : (64 + 4 * ty + (i - 4));
            float An = A[n0 + nl];
            #pragma unroll
            for (int j = 0; j < 8; ++j) {
                int kg = kt * BK + ((j < 4) ? (4 * tx + j) : (64 + 4 * tx + (j - 4)));
                float t1 = An - acc[i][j];
                float dist = t1 + ee[kg];
                if (dist < bestv[i]) { bestv[i] = dist; bestk[i] = kg; }  // strict <: first-min
            }
        }
    }
    // reduce across the 16 tx lanes sharing each n (tie -> lowest k; associative-exact)
    #pragma unroll
    for (int i = 0; i < 8; ++i) {
        float v = bestv[i];
        int   kk = bestk[i];
        #pragma unroll
        for (int off = 8; off >= 1; off >>= 1) {
            float ov = __shfl_xor(v, off, 64);
            int   ok = __shfl_xor(kk, off, 64);
            if (ov < v || (ov == v && ok < kk)) { v = ov; kk = ok; }
        }
        if (tx == 0) {
            int nl = (i < 4) ? (4 * ty + i) : (64 + 4 * ty + (i - 4));
            out[n0 + nl] = kk;
        }
    }
}

extern "C" void kernel_launch(void* const* d_in, const int* in_sizes, int n_in,
                              void* d_out, int out_size, void* d_ws, size_t ws_size,
                              hipStream_t stream) {
    const float* z   = (const float*)d_in[0];   // [16,256,64,64]
    const float* emb = (const float*)d_in[1];   // [1024,256]
    int* out = (int*)d_out;                     // [65536] int32

    float* wsA  = (float*)d_ws;                 // 65536 floats
    float* wsEE = wsA + N_TOT;                  // 1024 floats

    ee_kernel<<<K_DIM / 256, 256, 0, stream>>>(emb, wsEE);
    a_kernel<<<N_TOT / 256, 256, 0, stream>>>(z, wsA);
    vq_kernel<<<N_TOT / BN, 256, 0, stream>>>(z, emb, wsA, wsEE, out);
}

// Round 2
// 521.993 us; speedup vs baseline: 1.0207x; 1.0207x over previous
//
#include <hip/hip_runtime.h>

// VQ argmin: exact bit-level emulation of numpy fp32 reference:
//   A = np.sum(flat*flat, axis=1)        (numpy pairwise-sum tree, fp32)
//   M2 = (2*flat) @ emb.T                (BLAS: sequential fp32 fma chain over d)
//   d = (A - M2) + ee;  argmin_k (first-min ties)
// z_e_x: [B=16, D=256, H=64, W=64] fp32; embedding: [K=1024, D=256] fp32
// out: int32 [65536]
//
// R2: vq_kernel restructured — 8n x 16k register tile (BN=128, BK=256),
// double-buffered LDS + register prefetch (1 barrier/chunk), conflict-free
// e-staging. LDS:VALU per dd-round now 576:512 cyc/CU (was 384:256).

#define D_DIM 256
#define K_DIM 1024
#define HW    4096
#define N_TOT 65536
#define BN    128
#define BK    256           // k-tile per pass (4 passes)
#define DC    16            // d chunk staged in LDS
#define LDE   260           // es padded stride (4*65; odd/4 -> 2-way max on writes)

// ---- numpy pairwise_sum replication (n=256 = two 128-blocks of 8 accumulators)

__global__ void ee_kernel(const float* __restrict__ e, float* __restrict__ ee) {
#pragma clang fp contract(off)
    int k = blockIdx.x * blockDim.x + threadIdx.x;
    if (k >= K_DIM) return;
    const float* row = e + (size_t)k * D_DIM;
    float total = 0.0f;
    #pragma unroll
    for (int h = 0; h < 2; ++h) {
        const float* a = row + h * 128;
        float r[8];
        #pragma unroll
        for (int j = 0; j < 8; ++j) { float v = a[j]; r[j] = v * v; }
        #pragma unroll
        for (int i = 8; i < 128; i += 8) {
            #pragma unroll
            for (int j = 0; j < 8; ++j) { float v = a[i + j]; r[j] = r[j] + v * v; }
        }
        float s = ((r[0] + r[1]) + (r[2] + r[3])) + ((r[4] + r[5]) + (r[6] + r[7]));
        total = (h == 0) ? s : (total + s);
    }
    ee[k] = total;
}

__global__ void a_kernel(const float* __restrict__ z, float* __restrict__ A) {
#pragma clang fp contract(off)
    int n = blockIdx.x * blockDim.x + threadIdx.x;
    int b  = n >> 12;
    int hw = n & (HW - 1);
    const float* base = z + (size_t)b * D_DIM * HW + hw;
    float total = 0.0f;
    #pragma unroll
    for (int h = 0; h < 2; ++h) {
        float r[8];
        #pragma unroll
        for (int j = 0; j < 8; ++j) {
            float v = base[(size_t)(h * 128 + j) * HW];
            r[j] = v * v;
        }
        #pragma unroll
        for (int i = 8; i < 128; i += 8) {
            #pragma unroll
            for (int j = 0; j < 8; ++j) {
                float v = base[(size_t)(h * 128 + i + j) * HW];
                r[j] = r[j] + v * v;
            }
        }
        float s = ((r[0] + r[1]) + (r[2] + r[3])) + ((r[4] + r[5]) + (r[6] + r[7]));
        total = (h == 0) ? s : (total + s);
    }
    A[n] = total;
}

// ---- main kernel: 128n x 256k per block, 8x16 acc/thread, dbuf LDS + prefetch

__launch_bounds__(256, 2)
__global__ void vq_kernel(const float* __restrict__ z, const float* __restrict__ emb,
                          const float* __restrict__ A, const float* __restrict__ ee,
                          int* __restrict__ out) {
#pragma clang fp contract(off)
    __shared__ __align__(16) float zs[2][DC * BN];    // [buf][dd][n], holds 2*z
    __shared__ __align__(16) float es[2][DC * LDE];   // [buf][dd][k]

    const int tid = threadIdx.x;
    const int tx = tid & 15;          // k-group (16 lanes)
    const int ty = tid >> 4;          // n-group (16 groups)
    const int n0 = blockIdx.x * BN;
    const int b   = n0 >> 12;         // BN divides HW: tile never crosses batch
    const int hw0 = n0 & (HW - 1);
    const float* zbase = z + (size_t)b * D_DIM * HW + hw0;

    // staging thread-mappings (fixed per thread)
    const int zdl0 = tid >> 5, zn0 = (tid & 31) * 4;           // z piece 0
    const int zdl1 = (tid + 256) >> 5, zn1 = zn0;              // z piece 1 (tid+256: same n4)
    const int edq4 = (tid & 3) * 4;                            // d-quad within chunk
    const int ekb  = tid >> 2;                                 // k base (0..63)

    // per-thread n rows: nl(i) = 4*ty + (i&3) + 64*(i>>2)
    float An[8];
    #pragma unroll
    for (int i = 0; i < 8; ++i) An[i] = A[n0 + 4 * ty + (i & 3) + 64 * (i >> 2)];

    float bestv[8]; int bestk[8];
    #pragma unroll
    for (int i = 0; i < 8; ++i) { bestv[i] = 3.402823466e38f; bestk[i] = 0; }

    float acc[8][16];
    #pragma unroll
    for (int i = 0; i < 8; ++i)
        #pragma unroll
        for (int j = 0; j < 16; ++j) acc[i][j] = 0.0f;

    float4 zp0, zp1, ep0, ep1, ep2, ep3;

    // ---- prefetch chunk 0
    {
        const int d0 = 0, k0 = 0;
        zp0 = *(const float4*)(zbase + (size_t)(d0 + zdl0) * HW + zn0);
        zp1 = *(const float4*)(zbase + (size_t)(d0 + zdl1) * HW + zn1);
        const float* eb = emb + (size_t)(k0 + ekb) * D_DIM + d0 + edq4;
        ep0 = *(const float4*)(eb);
        ep1 = *(const float4*)(eb + 64 * D_DIM);
        ep2 = *(const float4*)(eb + 128 * D_DIM);
        ep3 = *(const float4*)(eb + 192 * D_DIM);
    }
    // ---- stage chunk 0 -> buf 0
    {
        float4 w0, w1;
        w0.x = 2.0f*zp0.x; w0.y = 2.0f*zp0.y; w0.z = 2.0f*zp0.z; w0.w = 2.0f*zp0.w;
        w1.x = 2.0f*zp1.x; w1.y = 2.0f*zp1.y; w1.z = 2.0f*zp1.z; w1.w = 2.0f*zp1.w;
        *(float4*)&zs[0][zdl0 * BN + zn0] = w0;
        *(float4*)&zs[0][zdl1 * BN + zn1] = w1;
        float* e0p = &es[0][edq4 * LDE + ekb];
        e0p[0*LDE +   0] = ep0.x; e0p[1*LDE +   0] = ep0.y; e0p[2*LDE +   0] = ep0.z; e0p[3*LDE +   0] = ep0.w;
        e0p[0*LDE +  64] = ep1.x; e0p[1*LDE +  64] = ep1.y; e0p[2*LDE +  64] = ep1.z; e0p[3*LDE +  64] = ep1.w;
        e0p[0*LDE + 128] = ep2.x; e0p[1*LDE + 128] = ep2.y; e0p[2*LDE + 128] = ep2.z; e0p[3*LDE + 128] = ep2.w;
        e0p[0*LDE + 192] = ep3.x; e0p[1*LDE + 192] = ep3.y; e0p[2*LDE + 192] = ep3.z; e0p[3*LDE + 192] = ep3.w;
    }

    // 64 chunks total: s = kt*16 + c, kt 0..3, c 0..15; chunk s lives in buf[s&1]
    for (int s = 0; s < 64; ++s) {
        const int cur = s & 1;

        // prefetch chunk s+1 into regs (latency hidden behind this chunk's fma)
        if (s < 63) {
            const int sn = s + 1;
            const int d0 = (sn & 15) * DC;
            const int k0 = (sn >> 4) * BK;
            zp0 = *(const float4*)(zbase + (size_t)(d0 + zdl0) * HW + zn0);
            zp1 = *(const float4*)(zbase + (size_t)(d0 + zdl1) * HW + zn1);
            const float* eb = emb + (size_t)(k0 + ekb) * D_DIM + d0 + edq4;
            ep0 = *(const float4*)(eb);
            ep1 = *(const float4*)(eb + 64 * D_DIM);
            ep2 = *(const float4*)(eb + 128 * D_DIM);
            ep3 = *(const float4*)(eb + 192 * D_DIM);
        }

        __syncthreads();   // buf[cur] writes visible; all readers of buf[cur^1] done

        // compute chunk s from buf[cur]; d ascending preserves the exact chain
        #pragma unroll 4
        for (int dd = 0; dd < DC; ++dd) {
            const float* zr0p = &zs[cur][dd * BN + 4 * ty];
            float4 z0 = *(const float4*)zr0p;
            float4 z1 = *(const float4*)(zr0p + 64);
            const float* erp = &es[cur][dd * LDE + 4 * tx];
            float4 e0 = *(const float4*)(erp);
            float4 e1 = *(const float4*)(erp + 64);
            float4 e2 = *(const float4*)(erp + 128);
            float4 e3 = *(const float4*)(erp + 192);
            float zr[8]  = {z0.x, z0.y, z0.z, z0.w, z1.x, z1.y, z1.z, z1.w};
            float er[16] = {e0.x, e0.y, e0.z, e0.w, e1.x, e1.y, e1.z, e1.w,
                            e2.x, e2.y, e2.z, e2.w, e3.x, e3.y, e3.z, e3.w};
            #pragma unroll
            for (int i = 0; i < 8; ++i)
                #pragma unroll
                for (int j = 0; j < 16; ++j)
                    acc[i][j] = fmaf(zr[i], er[j], acc[i][j]);
        }

        // stage chunk s+1 -> buf[cur^1] (disjoint from buf[cur] being read)
        if (s < 63) {
            const int nxt = cur ^ 1;
            float4 w0, w1;
            w0.x = 2.0f*zp0.x; w0.y = 2.0f*zp0.y; w0.z = 2.0f*zp0.z; w0.w = 2.0f*zp0.w;
            w1.x = 2.0f*zp1.x; w1.y = 2.0f*zp1.y; w1.z = 2.0f*zp1.z; w1.w = 2.0f*zp1.w;
            *(float4*)&zs[nxt][zdl0 * BN + zn0] = w0;
            *(float4*)&zs[nxt][zdl1 * BN + zn1] = w1;
            float* e0p = &es[nxt][edq4 * LDE + ekb];
            e0p[0*LDE +   0] = ep0.x; e0p[1*LDE +   0] = ep0.y; e0p[2*LDE +   0] = ep0.z; e0p[3*LDE +   0] = ep0.w;
            e0p[0*LDE +  64] = ep1.x; e0p[1*LDE +  64] = ep1.y; e0p[2*LDE +  64] = ep1.z; e0p[3*LDE +  64] = ep1.w;
            e0p[0*LDE + 128] = ep2.x; e0p[1*LDE + 128] = ep2.y; e0p[2*LDE + 128] = ep2.z; e0p[3*LDE + 128] = ep2.w;
            e0p[0*LDE + 192] = ep3.x; e0p[1*LDE + 192] = ep3.y; e0p[2*LDE + 192] = ep3.z; e0p[3*LDE + 192] = ep3.w;
        }

        // k-tile boundary: fold this kt into the running argmin, exact numpy chain
        if ((s & 15) == 15) {
            const int kt = s >> 4;
            float eev[16];
            #pragma unroll
            for (int j = 0; j < 16; ++j)
                eev[j] = ee[kt * BK + 4 * tx + (j & 3) + 64 * (j >> 2)];
            #pragma unroll
            for (int i = 0; i < 8; ++i) {
                const float a = An[i];
                #pragma unroll
                for (int j = 0; j < 16; ++j) {   // k ascending in j: ties -> lowest k
                    const int kg = kt * BK + 4 * tx + (j & 3) + 64 * (j >> 2);
                    const float t1 = a - acc[i][j];
                    const float dist = t1 + eev[j];
                    if (dist < bestv[i]) { bestv[i] = dist; bestk[i] = kg; }
                    acc[i][j] = 0.0f;
                }
            }
        }
    }

    // reduce across the 16 tx lanes per n (lexicographic: tie -> lowest k)
    #pragma unroll
    for (int i = 0; i < 8; ++i) {
        float v = bestv[i];
        int   kk = bestk[i];
        #pragma unroll
        for (int off = 8; off >= 1; off >>= 1) {
            float ov = __shfl_xor(v, off, 64);
            int   ok = __shfl_xor(kk, off, 64);
            if (ov < v || (ov == v && ok < kk)) { v = ov; kk = ok; }
        }
        if (tx == 0) out[n0 + 4 * ty + (i & 3) + 64 * (i >> 2)] = kk;
    }
}

extern "C" void kernel_launch(void* const* d_in, const int* in_sizes, int n_in,
                              void* d_out, int out_size, void* d_ws, size_t ws_size,
                              hipStream_t stream) {
    const float* z   = (const float*)d_in[0];   // [16,256,64,64]
    const float* emb = (const float*)d_in[1];   // [1024,256]
    int* out = (int*)d_out;                     // [65536] int32

    float* wsA  = (float*)d_ws;                 // 65536 floats
    float* wsEE = wsA + N_TOT;                  // 1024 floats

    ee_kernel<<<K_DIM / 256, 256, 0, stream>>>(emb, wsEE);
    a_kernel<<<N_TOT / 256, 256, 0, stream>>>(z, wsA);
    vq_kernel<<<N_TOT / BN, 256, 0, stream>>>(z, emb, wsA, wsEE, out);
}

// Round 3
// 511.873 us; speedup vs baseline: 1.0409x; 1.0198x over previous
//
#include <hip/hip_runtime.h>

// VQ argmin: exact bit-level emulation of numpy fp32 reference:
//   A  = np.sum(flat*flat, axis=1)     (numpy pairwise-sum tree, fp32)
//   M2 = (2*flat) @ emb.T              (BLAS: sequential fp32 fma chain over d)
//   dist = (A - M2) + ee;  argmin_k (first-min ties)
// z_e_x: [B=16, D=256, H=64, W=64] fp32; embedding: [K=1024, D=256] fp32
// out: int32 [65536]
//
// R3: LDS-free GEMV-broadcast structure. Lanes map to n only (z loads
// coalesced, z chunk ping-pong in VGPRs); e is wave-uniform -> s_load into
// SGPRs, consumed directly by v_fma_f32 (1 SGPR operand). No LDS, no
// barriers. Split-4 over K (1024 blocks = 4/CU), exact lexicographic combine.
// x2 folded into transposed eT ((2z)*e == z*(2e) bitwise).

#define D_DIM  256
#define K_DIM  1024
#define HW     4096
#define N_TOT  65536
#define NSPLIT 4
#define KSPL   (K_DIM / NSPLIT)   // 256
#define KT     64                 // k-tile held in acc regs
#define NKT    (KSPL / KT)        // 4
#define F32MAX 3.402823466e38f

// ---- numpy pairwise_sum replication (n=256 = two 128-blocks of 8 accumulators)

__global__ void ee_kernel(const float* __restrict__ e, float* __restrict__ ee) {
#pragma clang fp contract(off)
    int k = blockIdx.x * blockDim.x + threadIdx.x;
    if (k >= K_DIM) return;
    const float* row = e + (size_t)k * D_DIM;
    float total = 0.0f;
    #pragma unroll
    for (int h = 0; h < 2; ++h) {
        const float* a = row + h * 128;
        float r[8];
        #pragma unroll
        for (int j = 0; j < 8; ++j) { float v = a[j]; r[j] = v * v; }
        #pragma unroll
        for (int i = 8; i < 128; i += 8) {
            #pragma unroll
            for (int j = 0; j < 8; ++j) { float v = a[i + j]; r[j] = r[j] + v * v; }
        }
        float s = ((r[0] + r[1]) + (r[2] + r[3])) + ((r[4] + r[5]) + (r[6] + r[7]));
        total = (h == 0) ? s : (total + s);
    }
    ee[k] = total;
}

__global__ void a_kernel(const float* __restrict__ z, float* __restrict__ A) {
#pragma clang fp contract(off)
    int n = blockIdx.x * blockDim.x + threadIdx.x;
    int b  = n >> 12;
    int hw = n & (HW - 1);
    const float* base = z + (size_t)b * D_DIM * HW + hw;
    float total = 0.0f;
    #pragma unroll
    for (int h = 0; h < 2; ++h) {
        float r[8];
        #pragma unroll
        for (int j = 0; j < 8; ++j) {
            float v = base[(size_t)(h * 128 + j) * HW];
            r[j] = v * v;
        }
        #pragma unroll
        for (int i = 8; i < 128; i += 8) {
            #pragma unroll
            for (int j = 0; j < 8; ++j) {
                float v = base[(size_t)(h * 128 + i + j) * HW];
                r[j] = r[j] + v * v;
            }
        }
        float s = ((r[0] + r[1]) + (r[2] + r[3])) + ((r[4] + r[5]) + (r[6] + r[7]));
        total = (h == 0) ? s : (total + s);
    }
    A[n] = total;
}

// ---- transpose + fold the exact x2: eT[d][k] = 2*emb[k][d]

__global__ void et_kernel(const float* __restrict__ e, float* __restrict__ eT) {
    int k = blockIdx.x;       // 0..1023
    int d = threadIdx.x;      // 0..255
    eT[(size_t)d * K_DIM + k] = 2.0f * e[(size_t)k * D_DIM + d];
}

// ---- main: 1 n per thread, e broadcast via SGPRs, 64-k acc tile, no LDS

__launch_bounds__(256, 4)
__global__ void vq_partial(const float* __restrict__ z, const float* __restrict__ eT,
                           const float* __restrict__ A, const float* __restrict__ ee,
                           float* __restrict__ pv, int* __restrict__ pk) {
#pragma clang fp contract(off)
    const int tid  = threadIdx.x;
    const int s    = blockIdx.x & (NSPLIT - 1);   // co-resident blocks share s
    const int slab = blockIdx.x >> 2;
    const int n    = slab * 256 + tid;
    const int b    = n >> 12;
    const int hw   = n & (HW - 1);
    const float* __restrict__ zp = z + (size_t)b * D_DIM * HW + hw;
    const int kb0 = s * KSPL;

    const float An = A[n];
    float bestv = F32MAX;
    int   bestk = 0;

    // z chunk ping-pong: 8 d's per half, prefetched ~1 half ahead.
    // z is independent of kt, so the (mod 256) wrap re-primes za for the
    // next kt's d=0..7 automatically.
    float za[8], zb[8];
    #pragma unroll
    for (int i = 0; i < 8; ++i) za[i] = zp[(size_t)i * HW];

    #pragma unroll 1
    for (int kt = 0; kt < NKT; ++kt) {
        const int kbase = kb0 + kt * KT;
        float acc[KT];
        #pragma unroll
        for (int j = 0; j < KT; ++j) acc[j] = 0.0f;

        #pragma unroll 1
        for (int it = 0; it < 16; ++it) {
            const int base = it * 16;
            // prefetch d = base+8 .. base+15
            #pragma unroll
            for (int i = 0; i < 8; ++i)
                zb[i] = zp[(size_t)((base + 8 + i) & (D_DIM - 1)) * HW];
            // compute d = base .. base+7 (ascending: exact chain)
            #pragma unroll
            for (int dd = 0; dd < 8; ++dd) {
                const float zv = za[dd];
                const float* __restrict__ er = eT + (size_t)(base + dd) * K_DIM + kbase;
                #pragma unroll
                for (int j = 0; j < KT; ++j)
                    acc[j] = fmaf(zv, er[j], acc[j]);   // er[j] -> SGPR operand
            }
            // prefetch d = base+16 .. base+23 (mod 256)
            #pragma unroll
            for (int i = 0; i < 8; ++i)
                za[i] = zp[(size_t)((base + 16 + i) & (D_DIM - 1)) * HW];
            // compute d = base+8 .. base+15
            #pragma unroll
            for (int dd = 0; dd < 8; ++dd) {
                const float zv = zb[dd];
                const float* __restrict__ er = eT + (size_t)(base + 8 + dd) * K_DIM + kbase;
                #pragma unroll
                for (int j = 0; j < KT; ++j)
                    acc[j] = fmaf(zv, er[j], acc[j]);
            }
        }

        // epilogue: dist = (An - M2) + ee, k ascending -> first-min ties
        #pragma unroll
        for (int j = 0; j < KT; ++j) {
            const float dist = (An - acc[j]) + ee[kbase + j];
            if (dist < bestv) { bestv = dist; bestk = kbase + j; }
        }
    }

    pv[(size_t)s * N_TOT + n] = bestv;
    pk[(size_t)s * N_TOT + n] = bestk;
}

// ---- exact cross-split combine (splits ascending in k; strict < keeps lowest)

__global__ void combine_kernel(const float* __restrict__ pv, const int* __restrict__ pk,
                               int* __restrict__ out) {
    int n = blockIdx.x * blockDim.x + threadIdx.x;
    float bv = pv[n];
    int   bk = pk[n];
    #pragma unroll
    for (int s2 = 1; s2 < NSPLIT; ++s2) {
        float v = pv[(size_t)s2 * N_TOT + n];
        int   k = pk[(size_t)s2 * N_TOT + n];
        if (v < bv) { bv = v; bk = k; }
    }
    out[n] = bk;
}

extern "C" void kernel_launch(void* const* d_in, const int* in_sizes, int n_in,
                              void* d_out, int out_size, void* d_ws, size_t ws_size,
                              hipStream_t stream) {
    const float* z   = (const float*)d_in[0];   // [16,256,64,64]
    const float* emb = (const float*)d_in[1];   // [1024,256]
    int* out = (int*)d_out;                     // [65536] int32

    float* wsA  = (float*)d_ws;                     // 65536
    float* wsEE = wsA + N_TOT;                      // 1024
    float* wsET = wsEE + K_DIM;                     // 262144
    float* wsPV = wsET + (size_t)D_DIM * K_DIM;     // 4*65536
    int*   wsPK = (int*)(wsPV + (size_t)NSPLIT * N_TOT);  // 4*65536

    et_kernel<<<K_DIM, 256, 0, stream>>>(emb, wsET);
    ee_kernel<<<K_DIM / 256, 256, 0, stream>>>(emb, wsEE);
    a_kernel<<<N_TOT / 256, 256, 0, stream>>>(z, wsA);
    vq_partial<<<N_TOT / 256 * NSPLIT, 256, 0, stream>>>(z, wsET, wsA, wsEE, wsPV, wsPK);
    combine_kernel<<<N_TOT / 256, 256, 0, stream>>>(wsPV, wsPK, out);
}